// Round 2
// baseline (179.602 us; speedup 1.0000x reference)
//
#include <hip/hip_runtime.h>
#include <math.h>

#define K_DIM 2048
#define E_DIM 64
#define BM 16            // rows per block
#define NW 8             // waves per block (512 threads)
#define KW (K_DIM / NW)  // 256 K per wave (split-K across waves)
#define KC 32            // K per inner iteration (w regs per lane)

// Pack w[e][k] (row-major K) into wp[k4][e] = float4{w[e][4k4..4k4+3]}
// so per-lane (lane=expert) loads of 4 consecutive k are coalesced across lanes.
__global__ void transpose_w_kernel(const float* __restrict__ w, float4* __restrict__ wp) {
    int tid = (int)blockIdx.x * 256 + (int)threadIdx.x;  // 32768 threads
    int e  = tid >> 9;     // 0..63
    int k4 = tid & 511;    // 0..511
    float4 v = *(const float4*)(w + (size_t)e * K_DIM + (size_t)k4 * 4);
    wp[(size_t)k4 * E_DIM + e] = v;
}

__global__ __launch_bounds__(512, 4) void gate_kernel(
    const float* __restrict__ x,
    const float* __restrict__ wsrc,
    int strideE, int strideK4,        // float-unit strides: addr = e*strideE + k4*strideK4
    float* __restrict__ out, int M)
{
    __shared__ float red[NW][BM][E_DIM];   // 32 KB partial-logit reduction

    const int t    = (int)threadIdx.x;
    const int lane = t & 63;
    const int wave = __builtin_amdgcn_readfirstlane(t >> 6);  // force wave-uniform
    const int rowbase = (int)blockIdx.x * BM;
    const int k0w  = wave * KW;

    float acc[BM];
    #pragma unroll
    for (int r = 0; r < BM; ++r) acc[r] = 0.f;

    const float* wbase = wsrc + (size_t)lane * strideE + (size_t)(k0w / 4) * strideK4;

    for (int it = 0; it < KW / KC; ++it) {
        // w chunk for this lane's expert: KC floats in VGPRs
        float4 wv[KC / 4];
        #pragma unroll
        for (int i = 0; i < KC / 4; ++i)
            wv[i] = *(const float4*)(wbase + (size_t)(it * (KC / 4) + i) * strideK4);

        // x base for this wave's K-chunk (wave-uniform address -> s_load path)
        const float* xk = x + (size_t)rowbase * K_DIM + (size_t)k0w + (size_t)it * KC;

        #pragma unroll
        for (int r = 0; r < BM; ++r) {
            const float4* xr = (const float4*)(xk + (size_t)r * K_DIM);
            #pragma unroll
            for (int i = 0; i < KC / 4; ++i) {
                float4 xv = xr[i];   // wave-uniform -> SGPRs
                acc[r] = fmaf(xv.x, wv[i].x, acc[r]);
                acc[r] = fmaf(xv.y, wv[i].y, acc[r]);
                acc[r] = fmaf(xv.z, wv[i].z, acc[r]);
                acc[r] = fmaf(xv.w, wv[i].w, acc[r]);
            }
        }
    }

    // cross-wave (split-K) reduction via LDS; layout conflict-free (lane contiguous)
    #pragma unroll
    for (int r = 0; r < BM; ++r) red[wave][r][lane] = acc[r];
    __syncthreads();

    // gating: each wave finishes BM/NW rows; lane == expert
    #pragma unroll 1
    for (int rr = 0; rr < BM / NW; ++rr) {
        const int r = wave * (BM / NW) + rr;
        float l = 0.f;
        #pragma unroll
        for (int wv_ = 0; wv_ < NW; ++wv_) l += red[wv_][r][lane];

        // row max
        float m = l;
        #pragma unroll
        for (int off = 32; off >= 1; off >>= 1)
            m = fmaxf(m, __shfl_xor(m, off));

        // softmax denom
        float e = expf(l - m);
        float z = e;
        #pragma unroll
        for (int off = 32; off >= 1; off >>= 1)
            z += __shfl_xor(z, off);
        const float p = e / z;

        // top-1 on probs, lowest-index tie-break
        float v1 = p; int i1 = lane;
        #pragma unroll
        for (int off = 32; off >= 1; off >>= 1) {
            float ov = __shfl_xor(v1, off);
            int   oi = __shfl_xor(i1, off);
            if (ov > v1 || (ov == v1 && oi < i1)) { v1 = ov; i1 = oi; }
        }

        // top-2: mask winner, argmax again
        float v2 = (lane == i1) ? -1.0f : p; int i2 = lane;
        #pragma unroll
        for (int off = 32; off >= 1; off >>= 1) {
            float ov = __shfl_xor(v2, off);
            int   oi = __shfl_xor(i2, off);
            if (ov > v2 || (ov == v2 && oi < i2)) { v2 = ov; i2 = oi; }
        }

        if (lane == 0) {
            const size_t row = (size_t)rowbase + r;
            const float denom = v1 + v2 + 1e-9f;
            out[row * 2 + 0] = v1 / denom;
            out[row * 2 + 1] = v2 / denom;
            out[(size_t)M * 2 + row * 2 + 0] = (float)i1;
            out[(size_t)M * 2 + row * 2 + 1] = (float)i2;
        }
    }
}

extern "C" void kernel_launch(void* const* d_in, const int* in_sizes, int n_in,
                              void* d_out, int out_size, void* d_ws, size_t ws_size,
                              hipStream_t stream)
{
    const float* x = (const float*)d_in[0];
    const float* w = (const float*)d_in[1];
    float* out = (float*)d_out;
    const int M = in_sizes[0] / K_DIM;        // 16384 rows
    const int grid = M / BM;                  // 1024 blocks

    const size_t wp_bytes = (size_t)(K_DIM / 4) * E_DIM * sizeof(float4);  // 512 KB
    if (ws_size >= wp_bytes) {
        transpose_w_kernel<<<(E_DIM * K_DIM / 4) / 256, 256, 0, stream>>>(w, (float4*)d_ws);
        // wp float addr = (k4*64 + e)*4  -> strideE = 4, strideK4 = 256
        gate_kernel<<<grid, 512, 0, stream>>>(x, (const float*)d_ws, 4, 256, out, M);
    } else {
        // fallback: original layout, addr = e*2048 + k4*4
        gate_kernel<<<grid, 512, 0, stream>>>(x, w, K_DIM, 4, out, M);
    }
}

// Round 3
// 47.493 us; speedup vs baseline: 3.7816x; 3.7816x over previous
//
#include <hip/hip_runtime.h>
#include <math.h>

#define K_DIM 2048
#define E_DIM 64
#define BM 32                 // rows per block
#define NW 4                  // waves per block (256 threads)
#define KW (K_DIM / NW)       // 512 K per wave (split-K)
#define KS 32                 // K per MFMA step
#define NSTEP (KW / KS)       // 16 steps per wave
#define WSCALE 64.0f          // power-of-2 scale so w_lo stays fp16-normal

typedef _Float16 f16x8 __attribute__((ext_vector_type(8)));
typedef float    f32x4 __attribute__((ext_vector_type(4)));

// Pack w[e][k] fp32 -> fp16 hi/lo fragment streams in exact MFMA B order:
// frag index f = (kk*4 + ntile)*64 + lane ; halves j=0..7 are k = kk*32 + (lane>>4)*8 + j
// of col = ntile*16 + (lane&15). hi at wpk[0..], lo at wpk + K_DIM*E_DIM.
__global__ void pack_w_kernel(const float* __restrict__ w, _Float16* __restrict__ wpk) {
    int tid  = (int)blockIdx.x * 256 + (int)threadIdx.x;   // 16384 threads
    int lane = tid & 63;
    int n    = (tid >> 6) & 3;
    int kk   = tid >> 8;                                   // 0..63
    int col  = n * 16 + (lane & 15);
    int k    = kk * 32 + (lane >> 4) * 8;
    const float* src = w + (size_t)col * K_DIM + k;
    _Float16* hi = wpk + (size_t)tid * 8;
    _Float16* lo = hi + (size_t)K_DIM * E_DIM;
    #pragma unroll
    for (int j = 0; j < 8; ++j) {
        float v = src[j] * WSCALE;
        _Float16 h = (_Float16)v;
        hi[j] = h;
        lo[j] = (_Float16)(v - (float)h);
    }
}

template<int PACKED>
__global__ __launch_bounds__(256, 2) void mfma_gate_kernel(
    const float* __restrict__ x,
    const float* __restrict__ w,
    const _Float16* __restrict__ wpk,
    float* __restrict__ out, int M)
{
    __shared__ float red[NW][BM][E_DIM + 1];   // fp32 partial logits, stride 65

    const int t    = (int)threadIdx.x;
    const int lane = t & 63;
    const int wave = __builtin_amdgcn_readfirstlane(t >> 6);
    const int lr   = lane & 15;        // A row / B col within tile
    const int ks   = lane >> 4;        // k-subgroup (8 halves each)
    const int rowbase = (int)blockIdx.x * BM;
    const size_t k0 = (size_t)wave * KW;

    f32x4 acc[2][4];
    #pragma unroll
    for (int m = 0; m < 2; ++m)
        #pragma unroll
        for (int n = 0; n < 4; ++n)
            acc[m][n] = (f32x4){0.f, 0.f, 0.f, 0.f};

    const float* xa = x + (size_t)(rowbase + lr) * K_DIM + k0 + (size_t)ks * 8;
    const _Float16* wph = wpk + ((size_t)(wave * NSTEP) * 4 * 64 + lane) * 8;
    const _Float16* wpl = wph + (size_t)K_DIM * E_DIM;

    for (int s = 0; s < NSTEP; ++s) {
        // ---- A: load fp32, split to fp16 hi/lo in registers ----
        f16x8 ah[2], al[2];
        #pragma unroll
        for (int m = 0; m < 2; ++m) {
            const float* p = xa + (size_t)m * 16 * K_DIM + (size_t)s * KS;
            float4 u0 = *(const float4*)p;
            float4 u1 = *(const float4*)(p + 4);
            float uu[8] = {u0.x, u0.y, u0.z, u0.w, u1.x, u1.y, u1.z, u1.w};
            #pragma unroll
            for (int j = 0; j < 8; ++j) {
                _Float16 h = (_Float16)uu[j];
                ah[m][j] = h;
                al[m][j] = (_Float16)(uu[j] - (float)h);
            }
        }
        // ---- B fragments ----
        f16x8 bh[4], bl[4];
        if (PACKED) {
            #pragma unroll
            for (int n = 0; n < 4; ++n) {
                bh[n] = *(const f16x8*)(wph + ((size_t)s * 4 + n) * 64 * 8);
                bl[n] = *(const f16x8*)(wpl + ((size_t)s * 4 + n) * 64 * 8);
            }
        } else {
            #pragma unroll
            for (int n = 0; n < 4; ++n) {
                const float* p = w + (size_t)(n * 16 + lr) * K_DIM + k0 + (size_t)s * KS + (size_t)ks * 8;
                float4 u0 = *(const float4*)p;
                float4 u1 = *(const float4*)(p + 4);
                float uu[8] = {u0.x, u0.y, u0.z, u0.w, u1.x, u1.y, u1.z, u1.w};
                #pragma unroll
                for (int j = 0; j < 8; ++j) {
                    float v = uu[j] * WSCALE;
                    _Float16 h = (_Float16)v;
                    bh[n][j] = h;
                    bl[n][j] = (_Float16)(v - (float)h);
                }
            }
        }
        // ---- 24 MFMAs: hh + hl + lh (ll term ~2^-22, dropped) ----
        #pragma unroll
        for (int m = 0; m < 2; ++m)
            #pragma unroll
            for (int n = 0; n < 4; ++n) {
                acc[m][n] = __builtin_amdgcn_mfma_f32_16x16x32_f16(ah[m], bh[n], acc[m][n], 0, 0, 0);
                acc[m][n] = __builtin_amdgcn_mfma_f32_16x16x32_f16(ah[m], bl[n], acc[m][n], 0, 0, 0);
                acc[m][n] = __builtin_amdgcn_mfma_f32_16x16x32_f16(al[m], bh[n], acc[m][n], 0, 0, 0);
            }
    }

    // ---- split-K reduction in LDS (unscale by 1/WSCALE) ----
    const float inv = 1.0f / WSCALE;
    #pragma unroll
    for (int m = 0; m < 2; ++m)
        #pragma unroll
        for (int n = 0; n < 4; ++n)
            #pragma unroll
            for (int j = 0; j < 4; ++j)
                red[wave][m * 16 + ks * 4 + j][n * 16 + lr] = acc[m][n][j] * inv;
    __syncthreads();

    // ---- gating: each wave finishes BM/NW rows; lane == expert ----
    #pragma unroll 1
    for (int rr = 0; rr < BM / NW; ++rr) {
        const int r = wave * (BM / NW) + rr;
        float l = red[0][r][lane] + red[1][r][lane] + red[2][r][lane] + red[3][r][lane];

        float m = l;
        #pragma unroll
        for (int off = 32; off >= 1; off >>= 1)
            m = fmaxf(m, __shfl_xor(m, off));

        float e = expf(l - m);
        float z = e;
        #pragma unroll
        for (int off = 32; off >= 1; off >>= 1)
            z += __shfl_xor(z, off);
        const float p = e / z;

        float v1 = p; int i1 = lane;
        #pragma unroll
        for (int off = 32; off >= 1; off >>= 1) {
            float ov = __shfl_xor(v1, off);
            int   oi = __shfl_xor(i1, off);
            if (ov > v1 || (ov == v1 && oi < i1)) { v1 = ov; i1 = oi; }
        }

        float v2 = (lane == i1) ? -1.0f : p; int i2 = lane;
        #pragma unroll
        for (int off = 32; off >= 1; off >>= 1) {
            float ov = __shfl_xor(v2, off);
            int   oi = __shfl_xor(i2, off);
            if (ov > v2 || (ov == v2 && oi < i2)) { v2 = ov; i2 = oi; }
        }

        if (lane == 0) {
            const size_t row = (size_t)rowbase + r;
            const float denom = v1 + v2 + 1e-9f;
            out[row * 2 + 0] = v1 / denom;
            out[row * 2 + 1] = v2 / denom;
            out[(size_t)M * 2 + row * 2 + 0] = (float)i1;
            out[(size_t)M * 2 + row * 2 + 1] = (float)i2;
        }
    }
}

extern "C" void kernel_launch(void* const* d_in, const int* in_sizes, int n_in,
                              void* d_out, int out_size, void* d_ws, size_t ws_size,
                              hipStream_t stream)
{
    const float* x = (const float*)d_in[0];
    const float* w = (const float*)d_in[1];
    float* out = (float*)d_out;
    const int M = in_sizes[0] / K_DIM;          // 16384 rows
    const int grid = M / BM;                    // 512 blocks

    const size_t pack_bytes = (size_t)K_DIM * E_DIM * 2 * sizeof(_Float16);  // 512 KB
    if (ws_size >= pack_bytes) {
        pack_w_kernel<<<64, 256, 0, stream>>>(w, (_Float16*)d_ws);
        mfma_gate_kernel<1><<<grid, 256, 0, stream>>>(x, w, (const _Float16*)d_ws, out, M);
    } else {
        mfma_gate_kernel<0><<<grid, 256, 0, stream>>>(x, w, nullptr, out, M);
    }
}